// Round 12
// baseline (3924.656 us; speedup 1.0000x reference)
//
#include <hip/hip_runtime.h>
#include <hip/hip_bf16.h>
#include <cstddef>

#define NN 200000   // nodes
#define NE 400000   // edges
#define DD 128      // embed dim
#define NL 5        // layers
#define NG 1000     // graphs
#define BOND_V 5
#define BM 32             // rows per fused block
#define NBLK (NN / BM)    // 6250
#define MAXD 16           // padded edge slots per row (deg>16 -> serial fallback)
#define CHUNK 100         // pool chunk (2000 blocks)
#define NB_SCAN 200
#define CH 1000
#define NSH 16            // BN-stat shards
#define EPS 1e-5f
#define XS 136            // Xh/Xl row stride (shorts), 272B = 17*16 -> b128-aligned

typedef __bf16 bf16x8 __attribute__((ext_vector_type(8)));
typedef float floatx4 __attribute__((ext_vector_type(4)));

__device__ __forceinline__ unsigned short f2bf(float f) {
    unsigned int u = __float_as_uint(f);
    u = (u + 0x7fffu + ((u >> 16) & 1u)) >> 16;
    return (unsigned short)u;
}
__device__ __forceinline__ float bf2f(unsigned short s) {
    return __uint_as_float(((unsigned int)s) << 16);
}
__device__ __forceinline__ float4 bf4_to_f4(uint2 v) {
    float4 o;
    o.x = __uint_as_float(v.x << 16);
    o.y = __uint_as_float(v.x & 0xffff0000u);
    o.z = __uint_as_float(v.y << 16);
    o.w = __uint_as_float(v.y & 0xffff0000u);
    return o;
}
__device__ __forceinline__ float4 actv4(float4 h, float4 sc, float4 sh) {
    float4 o;
    o.x = fmaxf(0.f, h.x * sc.x + sh.x);
    o.y = fmaxf(0.f, h.y * sc.y + sh.y);
    o.z = fmaxf(0.f, h.z * sc.z + sh.z);
    o.w = fmaxf(0.f, h.w * sc.w + sh.w);
    return o;
}

// ---------------- merged setup: degree cnt, graph cnt, W split ----------------
__global__ void k_setup1(const int* __restrict__ dst, int* __restrict__ cnt,
                         const int* __restrict__ n2g, float* __restrict__ gcnt,
                         const float* __restrict__ W, unsigned short* __restrict__ Wht,
                         unsigned short* __restrict__ Wlt) {
    int e = blockIdx.x * blockDim.x + threadIdx.x;
    if (e < NE) atomicAdd(&cnt[dst[e]], 1);
    if (e < NN) atomicAdd(&gcnt[n2g[e]], 1.0f);
    if (e < NL * DD * DD) {
        int l = e / (DD * DD), rem = e % (DD * DD);
        int k = rem / DD, n = rem % DD;
        float v = W[e];
        unsigned short hb = f2bf(v);
        unsigned short lb = f2bf(v - bf2f(hb));
        size_t o = (size_t)l * DD * DD + (size_t)n * DD + k;
        Wht[o] = hb; Wlt[o] = lb;
    }
}

// ---------------- CSR build ----------------
__global__ void k_scan1(const int* __restrict__ cnt, int* __restrict__ bsum) {
    __shared__ int sh[256];
    int b = blockIdx.x, t = threadIdx.x;
    int s = 0;
    if (t < CH / 4) {
        int base = b * CH + t * 4;
        s = cnt[base] + cnt[base + 1] + cnt[base + 2] + cnt[base + 3];
    }
    sh[t] = s;
    __syncthreads();
    if (t == 0) {
        int tot = 0;
        for (int i = 0; i < CH / 4; i++) tot += sh[i];
        bsum[b] = tot;
    }
}

__global__ void k_scan2(const int* __restrict__ bsum, int* __restrict__ bpre,
                        int* __restrict__ off) {
    if (threadIdx.x == 0) {
        int run = 0;
        for (int i = 0; i < NB_SCAN; i++) { bpre[i] = run; run += bsum[i]; }
        off[NN] = NE;
    }
}

__global__ void k_scan3(const int* __restrict__ cnt, const int* __restrict__ bpre,
                        int* __restrict__ off, int* __restrict__ cur,
                        float* __restrict__ rdeg) {
    __shared__ int sh[256];
    int b = blockIdx.x, t = threadIdx.x;
    int base = b * CH + t * 4;
    int c0 = 0, c1 = 0, c2 = 0, c3 = 0, s = 0;
    if (t < CH / 4) {
        c0 = cnt[base]; c1 = cnt[base + 1]; c2 = cnt[base + 2]; c3 = cnt[base + 3];
        s = c0 + c1 + c2 + c3;
    }
    sh[t] = s;
    __syncthreads();
    if (t == 0) {
        int run = bpre[b];
        for (int i = 0; i < CH / 4; i++) { int v = sh[i]; sh[i] = run; run += v; }
    }
    __syncthreads();
    if (t < CH / 4) {
        int run = sh[t];
        off[base] = run; cur[base] = run; run += c0;
        off[base + 1] = run; cur[base + 1] = run; run += c1;
        off[base + 2] = run; cur[base + 2] = run; run += c2;
        off[base + 3] = run; cur[base + 3] = run;
        rdeg[base]     = 1.0f / (float)(c0 + 1);
        rdeg[base + 1] = 1.0f / (float)(c1 + 1);
        rdeg[base + 2] = 1.0f / (float)(c2 + 1);
        rdeg[base + 3] = 1.0f / (float)(c3 + 1);
    }
}

__global__ void k_bucket(const int* __restrict__ src, const int* __restrict__ dst,
                         const int* __restrict__ efeat, int* __restrict__ cur,
                         int* __restrict__ esrc, int* __restrict__ eft) {
    int e = blockIdx.x * blockDim.x + threadIdx.x;
    if (e < NE) {
        int p = atomicAdd(&cur[dst[e]], 1);
        esrc[p] = src[e];
        eft[p] = efeat[e];
    }
}

// ---------------- degree-sorted padded edge lists ----------------
// pent[b][j][32] = src | feat<<18 (layers 1+); pent0 = nfeat[src] | feat<<18 (layer 0)
// sentinel feat=5 (zero edge row, weight 0).
__global__ void k_pad(const int* __restrict__ off, const int* __restrict__ esrc,
                      const int* __restrict__ eft, const int* __restrict__ nfeat,
                      int* __restrict__ pent, int* __restrict__ pent0,
                      int* __restrict__ bperm, int* __restrict__ gmax) {
    __shared__ int offL[BM + 1];
    __shared__ int degS[BM];
    __shared__ int sortIdx[BM];
    __shared__ int gmaxS[8];
    int b = blockIdx.x, tid = threadIdx.x;
    if (tid <= BM) offL[tid] = off[b * BM + tid];
    __syncthreads();
    if (tid < BM) degS[tid] = offL[tid + 1] - offL[tid];
    __syncthreads();
    if (tid < BM) {
        int d = degS[tid], rank = 0;
        #pragma unroll
        for (int j = 0; j < BM; j++)
            rank += (degS[j] > d) || (degS[j] == d && j < tid);
        sortIdx[rank] = tid;
    }
    __syncthreads();
    if (tid < 8) {
        int g = degS[sortIdx[tid * 4]];   // sorted desc -> first in group is max
        gmaxS[tid] = g;
        gmax[b * 8 + tid] = g;
    }
    if (tid < BM) bperm[b * BM + tid] = sortIdx[tid];
    __syncthreads();
    for (int idx = tid; idx < BM * MAXD; idx += 256) {
        int p = idx & 31, j = idx >> 5, g = p >> 2;
        int gm = gmaxS[g]; if (gm > MAXD) gm = MAXD;
        if (j < gm) {
            int row = sortIdx[p];
            int d = degS[row];
            int v, v0;
            if (j < d) {
                int e = offL[row] + j;
                int s = esrc[e], f = eft[e];
                v = s | (f << 18);
                v0 = nfeat[s] | (f << 18);
            } else { v = (5 << 18); v0 = (5 << 18); }
            pent[(size_t)b * MAXD * BM + j * BM + p] = v;
            pent0[(size_t)b * MAXD * BM + j * BM + p] = v0;
        }
    }
}

// ---------------- fused layer (two-plane Xh/Xl, r9 structure) ----------------
// epilogue: sharded global-atomic BN stats + last-block finalize -> scale/shift
__global__ __launch_bounds__(256, 4)
void k_fused(const void* __restrict__ basep, const int* __restrict__ nfeat, int first,
             const int* __restrict__ off, const int* __restrict__ esrc,
             const int* __restrict__ eft, const int* __restrict__ pentsel,
             const int* __restrict__ bperm, const int* __restrict__ gmax,
             const float* __restrict__ eemb, const float* __restrict__ rdeg,
             const float* __restrict__ scP, const float* __restrict__ shP,
             const unsigned short* __restrict__ Wht, const unsigned short* __restrict__ Wlt,
             const float* __restrict__ bias,
             unsigned short* __restrict__ C,
             float* __restrict__ musum, int* __restrict__ cntL,
             const float* __restrict__ gamC, const float* __restrict__ betC,
             float* __restrict__ scO, float* __restrict__ shO) {
    __shared__ unsigned short Xh[BM * XS];   // 8704 B (reused as C repack buffer)
    __shared__ unsigned short Xl[BM * XS];   // 8704 B
    __shared__ float eSr[6 * DD];            // 3072 B: eS in gather, red in epilogue
    __shared__ int pentL[BM * MAXD];         // 2048 B
    __shared__ int offL[BM + 1];
    __shared__ int permL[BM];
    __shared__ int gmL[8];
    __shared__ int lastF;

    const float* baseF = (const float*)basep;                   // first: atom_emb fp32
    const unsigned short* baseB = (const unsigned short*)basep; // else: h bf16

    int tid = threadIdx.x;
    int n0 = blockIdx.x * BM;
    if (tid < 160) *(float4*)(eSr + tid * 4) = *(const float4*)(eemb + tid * 4);
    else if (tid < 192) *(float4*)(eSr + tid * 4) = (float4){0.f, 0.f, 0.f, 0.f};
    if (tid <= BM) offL[tid] = off[n0 + tid];
    if (tid < BM) permL[tid] = bperm[blockIdx.x * BM + tid];
    if (tid < 8) gmL[tid] = gmax[blockIdx.x * 8 + tid];
    {
        const int2* pg = (const int2*)(pentsel + (size_t)blockIdx.x * MAXD * BM);
        *(int2*)(pentL + tid * 2) = pg[tid];
    }

    int lane32 = tid & 31, grp = tid >> 5;
    int c4 = lane32 << 2;
    float4 sc4, sh4;
    if (!first) {
        sc4 = *(const float4*)(scP + c4);
        sh4 = *(const float4*)(shP + c4);
    }
    __syncthreads();

    int rows[4];
    #pragma unroll
    for (int i = 0; i < 4; i++) rows[i] = permL[grp * 4 + i];

    // ---- self-init ----
    float4 acc[4];
    #pragma unroll
    for (int i = 0; i < 4; i++) {
        int n = n0 + rows[i];
        if (first) {
            acc[i] = *(const float4*)(baseF + (size_t)nfeat[n] * DD + c4);
        } else {
            uint2 g = *(const uint2*)(baseB + (size_t)n * DD + c4);
            acc[i] = actv4(bf4_to_f4(g), sc4, sh4);
        }
    }

    // ---- lockstep padded edge loop, unrolled x2, pent from LDS ----
    int gmx = gmL[grp];
    int jmax = gmx < MAXD ? gmx : MAXD;
    const int* pL = pentL + grp * 4;
    int j = 0;
    if (first) {
        for (; j + 2 <= jmax; j += 2) {
            int a0 = pL[j*32+0], a1 = pL[j*32+1], a2 = pL[j*32+2], a3 = pL[j*32+3];
            int b0 = pL[j*32+32], b1 = pL[j*32+33], b2 = pL[j*32+34], b3 = pL[j*32+35];
            float4 ha0 = *(const float4*)(baseF + (size_t)(a0 & 0x3FFFF) * DD + c4);
            float4 ha1 = *(const float4*)(baseF + (size_t)(a1 & 0x3FFFF) * DD + c4);
            float4 ha2 = *(const float4*)(baseF + (size_t)(a2 & 0x3FFFF) * DD + c4);
            float4 ha3 = *(const float4*)(baseF + (size_t)(a3 & 0x3FFFF) * DD + c4);
            float4 hb0 = *(const float4*)(baseF + (size_t)(b0 & 0x3FFFF) * DD + c4);
            float4 hb1 = *(const float4*)(baseF + (size_t)(b1 & 0x3FFFF) * DD + c4);
            float4 hb2 = *(const float4*)(baseF + (size_t)(b2 & 0x3FFFF) * DD + c4);
            float4 hb3 = *(const float4*)(baseF + (size_t)(b3 & 0x3FFFF) * DD + c4);
            int fa0 = a0 >> 18, fa1 = a1 >> 18, fa2 = a2 >> 18, fa3 = a3 >> 18;
            int fb0 = b0 >> 18, fb1 = b1 >> 18, fb2 = b2 >> 18, fb3 = b3 >> 18;
            float wa0 = (fa0 == 5) ? 0.f : 1.f, wa1 = (fa1 == 5) ? 0.f : 1.f;
            float wa2 = (fa2 == 5) ? 0.f : 1.f, wa3 = (fa3 == 5) ? 0.f : 1.f;
            float wb0 = (fb0 == 5) ? 0.f : 1.f, wb1 = (fb1 == 5) ? 0.f : 1.f;
            float wb2 = (fb2 == 5) ? 0.f : 1.f, wb3 = (fb3 == 5) ? 0.f : 1.f;
            float4 ea0 = *(const float4*)(eSr + fa0 * DD + c4);
            float4 ea1 = *(const float4*)(eSr + fa1 * DD + c4);
            float4 ea2 = *(const float4*)(eSr + fa2 * DD + c4);
            float4 ea3 = *(const float4*)(eSr + fa3 * DD + c4);
            float4 eb0 = *(const float4*)(eSr + fb0 * DD + c4);
            float4 eb1 = *(const float4*)(eSr + fb1 * DD + c4);
            float4 eb2 = *(const float4*)(eSr + fb2 * DD + c4);
            float4 eb3 = *(const float4*)(eSr + fb3 * DD + c4);
            acc[0].x += (ha0.x + ea0.x) * wa0 + (hb0.x + eb0.x) * wb0;
            acc[0].y += (ha0.y + ea0.y) * wa0 + (hb0.y + eb0.y) * wb0;
            acc[0].z += (ha0.z + ea0.z) * wa0 + (hb0.z + eb0.z) * wb0;
            acc[0].w += (ha0.w + ea0.w) * wa0 + (hb0.w + eb0.w) * wb0;
            acc[1].x += (ha1.x + ea1.x) * wa1 + (hb1.x + eb1.x) * wb1;
            acc[1].y += (ha1.y + ea1.y) * wa1 + (hb1.y + eb1.y) * wb1;
            acc[1].z += (ha1.z + ea1.z) * wa1 + (hb1.z + eb1.z) * wb1;
            acc[1].w += (ha1.w + ea1.w) * wa1 + (hb1.w + eb1.w) * wb1;
            acc[2].x += (ha2.x + ea2.x) * wa2 + (hb2.x + eb2.x) * wb2;
            acc[2].y += (ha2.y + ea2.y) * wa2 + (hb2.y + eb2.y) * wb2;
            acc[2].z += (ha2.z + ea2.z) * wa2 + (hb2.z + eb2.z) * wb2;
            acc[2].w += (ha2.w + ea2.w) * wa2 + (hb2.w + eb2.w) * wb2;
            acc[3].x += (ha3.x + ea3.x) * wa3 + (hb3.x + eb3.x) * wb3;
            acc[3].y += (ha3.y + ea3.y) * wa3 + (hb3.y + eb3.y) * wb3;
            acc[3].z += (ha3.z + ea3.z) * wa3 + (hb3.z + eb3.z) * wb3;
            acc[3].w += (ha3.w + ea3.w) * wa3 + (hb3.w + eb3.w) * wb3;
        }
        for (; j < jmax; j++) {
            int a0 = pL[j*32+0], a1 = pL[j*32+1], a2 = pL[j*32+2], a3 = pL[j*32+3];
            float4 h0 = *(const float4*)(baseF + (size_t)(a0 & 0x3FFFF) * DD + c4);
            float4 h1 = *(const float4*)(baseF + (size_t)(a1 & 0x3FFFF) * DD + c4);
            float4 h2 = *(const float4*)(baseF + (size_t)(a2 & 0x3FFFF) * DD + c4);
            float4 h3 = *(const float4*)(baseF + (size_t)(a3 & 0x3FFFF) * DD + c4);
            int f0 = a0 >> 18, f1 = a1 >> 18, f2 = a2 >> 18, f3 = a3 >> 18;
            float w0 = (f0 == 5) ? 0.f : 1.f, w1 = (f1 == 5) ? 0.f : 1.f;
            float w2 = (f2 == 5) ? 0.f : 1.f, w3 = (f3 == 5) ? 0.f : 1.f;
            float4 e0 = *(const float4*)(eSr + f0 * DD + c4);
            float4 e1 = *(const float4*)(eSr + f1 * DD + c4);
            float4 e2 = *(const float4*)(eSr + f2 * DD + c4);
            float4 e3 = *(const float4*)(eSr + f3 * DD + c4);
            acc[0].x += (h0.x + e0.x) * w0; acc[0].y += (h0.y + e0.y) * w0;
            acc[0].z += (h0.z + e0.z) * w0; acc[0].w += (h0.w + e0.w) * w0;
            acc[1].x += (h1.x + e1.x) * w1; acc[1].y += (h1.y + e1.y) * w1;
            acc[1].z += (h1.z + e1.z) * w1; acc[1].w += (h1.w + e1.w) * w1;
            acc[2].x += (h2.x + e2.x) * w2; acc[2].y += (h2.y + e2.y) * w2;
            acc[2].z += (h2.z + e2.z) * w2; acc[2].w += (h2.w + e2.w) * w2;
            acc[3].x += (h3.x + e3.x) * w3; acc[3].y += (h3.y + e3.y) * w3;
            acc[3].z += (h3.z + e3.z) * w3; acc[3].w += (h3.w + e3.w) * w3;
        }
    } else {
        for (; j + 2 <= jmax; j += 2) {
            int a0 = pL[j*32+0], a1 = pL[j*32+1], a2 = pL[j*32+2], a3 = pL[j*32+3];
            int b0 = pL[j*32+32], b1 = pL[j*32+33], b2 = pL[j*32+34], b3 = pL[j*32+35];
            uint2 ga0 = *(const uint2*)(baseB + (size_t)(a0 & 0x3FFFF) * DD + c4);
            uint2 ga1 = *(const uint2*)(baseB + (size_t)(a1 & 0x3FFFF) * DD + c4);
            uint2 ga2 = *(const uint2*)(baseB + (size_t)(a2 & 0x3FFFF) * DD + c4);
            uint2 ga3 = *(const uint2*)(baseB + (size_t)(a3 & 0x3FFFF) * DD + c4);
            uint2 gb0 = *(const uint2*)(baseB + (size_t)(b0 & 0x3FFFF) * DD + c4);
            uint2 gb1 = *(const uint2*)(baseB + (size_t)(b1 & 0x3FFFF) * DD + c4);
            uint2 gb2 = *(const uint2*)(baseB + (size_t)(b2 & 0x3FFFF) * DD + c4);
            uint2 gb3 = *(const uint2*)(baseB + (size_t)(b3 & 0x3FFFF) * DD + c4);
            float4 ha0 = actv4(bf4_to_f4(ga0), sc4, sh4);
            float4 ha1 = actv4(bf4_to_f4(ga1), sc4, sh4);
            float4 ha2 = actv4(bf4_to_f4(ga2), sc4, sh4);
            float4 ha3 = actv4(bf4_to_f4(ga3), sc4, sh4);
            float4 hb0 = actv4(bf4_to_f4(gb0), sc4, sh4);
            float4 hb1 = actv4(bf4_to_f4(gb1), sc4, sh4);
            float4 hb2 = actv4(bf4_to_f4(gb2), sc4, sh4);
            float4 hb3 = actv4(bf4_to_f4(gb3), sc4, sh4);
            int fa0 = a0 >> 18, fa1 = a1 >> 18, fa2 = a2 >> 18, fa3 = a3 >> 18;
            int fb0 = b0 >> 18, fb1 = b1 >> 18, fb2 = b2 >> 18, fb3 = b3 >> 18;
            float wa0 = (fa0 == 5) ? 0.f : 1.f, wa1 = (fa1 == 5) ? 0.f : 1.f;
            float wa2 = (fa2 == 5) ? 0.f : 1.f, wa3 = (fa3 == 5) ? 0.f : 1.f;
            float wb0 = (fb0 == 5) ? 0.f : 1.f, wb1 = (fb1 == 5) ? 0.f : 1.f;
            float wb2 = (fb2 == 5) ? 0.f : 1.f, wb3 = (fb3 == 5) ? 0.f : 1.f;
            float4 ea0 = *(const float4*)(eSr + fa0 * DD + c4);
            float4 ea1 = *(const float4*)(eSr + fa1 * DD + c4);
            float4 ea2 = *(const float4*)(eSr + fa2 * DD + c4);
            float4 ea3 = *(const float4*)(eSr + fa3 * DD + c4);
            float4 eb0 = *(const float4*)(eSr + fb0 * DD + c4);
            float4 eb1 = *(const float4*)(eSr + fb1 * DD + c4);
            float4 eb2 = *(const float4*)(eSr + fb2 * DD + c4);
            float4 eb3 = *(const float4*)(eSr + fb3 * DD + c4);
            acc[0].x += (ha0.x + ea0.x) * wa0 + (hb0.x + eb0.x) * wb0;
            acc[0].y += (ha0.y + ea0.y) * wa0 + (hb0.y + eb0.y) * wb0;
            acc[0].z += (ha0.z + ea0.z) * wa0 + (hb0.z + eb0.z) * wb0;
            acc[0].w += (ha0.w + ea0.w) * wa0 + (hb0.w + eb0.w) * wb0;
            acc[1].x += (ha1.x + ea1.x) * wa1 + (hb1.x + eb1.x) * wb1;
            acc[1].y += (ha1.y + ea1.y) * wa1 + (hb1.y + eb1.y) * wb1;
            acc[1].z += (ha1.z + ea1.z) * wa1 + (hb1.z + eb1.z) * wb1;
            acc[1].w += (ha1.w + ea1.w) * wa1 + (hb1.w + eb1.w) * wb1;
            acc[2].x += (ha2.x + ea2.x) * wa2 + (hb2.x + eb2.x) * wb2;
            acc[2].y += (ha2.y + ea2.y) * wa2 + (hb2.y + eb2.y) * wb2;
            acc[2].z += (ha2.z + ea2.z) * wa2 + (hb2.z + eb2.z) * wb2;
            acc[2].w += (ha2.w + ea2.w) * wa2 + (hb2.w + eb2.w) * wb2;
            acc[3].x += (ha3.x + ea3.x) * wa3 + (hb3.x + eb3.x) * wb3;
            acc[3].y += (ha3.y + ea3.y) * wa3 + (hb3.y + eb3.y) * wb3;
            acc[3].z += (ha3.z + ea3.z) * wa3 + (hb3.z + eb3.z) * wb3;
            acc[3].w += (ha3.w + ea3.w) * wa3 + (hb3.w + eb3.w) * wb3;
        }
        for (; j < jmax; j++) {
            int a0 = pL[j*32+0], a1 = pL[j*32+1], a2 = pL[j*32+2], a3 = pL[j*32+3];
            uint2 g0 = *(const uint2*)(baseB + (size_t)(a0 & 0x3FFFF) * DD + c4);
            uint2 g1 = *(const uint2*)(baseB + (size_t)(a1 & 0x3FFFF) * DD + c4);
            uint2 g2 = *(const uint2*)(baseB + (size_t)(a2 & 0x3FFFF) * DD + c4);
            uint2 g3 = *(const uint2*)(baseB + (size_t)(a3 & 0x3FFFF) * DD + c4);
            float4 h0 = actv4(bf4_to_f4(g0), sc4, sh4);
            float4 h1 = actv4(bf4_to_f4(g1), sc4, sh4);
            float4 h2 = actv4(bf4_to_f4(g2), sc4, sh4);
            float4 h3 = actv4(bf4_to_f4(g3), sc4, sh4);
            int f0 = a0 >> 18, f1 = a1 >> 18, f2 = a2 >> 18, f3 = a3 >> 18;
            float w0 = (f0 == 5) ? 0.f : 1.f, w1 = (f1 == 5) ? 0.f : 1.f;
            float w2 = (f2 == 5) ? 0.f : 1.f, w3 = (f3 == 5) ? 0.f : 1.f;
            float4 e0 = *(const float4*)(eSr + f0 * DD + c4);
            float4 e1 = *(const float4*)(eSr + f1 * DD + c4);
            float4 e2 = *(const float4*)(eSr + f2 * DD + c4);
            float4 e3 = *(const float4*)(eSr + f3 * DD + c4);
            acc[0].x += (h0.x + e0.x) * w0; acc[0].y += (h0.y + e0.y) * w0;
            acc[0].z += (h0.z + e0.z) * w0; acc[0].w += (h0.w + e0.w) * w0;
            acc[1].x += (h1.x + e1.x) * w1; acc[1].y += (h1.y + e1.y) * w1;
            acc[1].z += (h1.z + e1.z) * w1; acc[1].w += (h1.w + e1.w) * w1;
            acc[2].x += (h2.x + e2.x) * w2; acc[2].y += (h2.y + e2.y) * w2;
            acc[2].z += (h2.z + e2.z) * w2; acc[2].w += (h2.w + e2.w) * w2;
            acc[3].x += (h3.x + e3.x) * w3; acc[3].y += (h3.y + e3.y) * w3;
            acc[3].z += (h3.z + e3.z) * w3; acc[3].w += (h3.w + e3.w) * w3;
        }
    }

    // ---- rare fallback: rows with deg > MAXD ----
    if (gmx > MAXD) {
        #pragma unroll
        for (int i = 0; i < 4; i++) {
            int row = rows[i];
            for (int e = offL[row] + MAXD; e < offL[row + 1]; e++) {
                int s = esrc[e], f = eft[e];
                float4 hv;
                if (first) {
                    hv = *(const float4*)(baseF + (size_t)nfeat[s] * DD + c4);
                } else {
                    uint2 g = *(const uint2*)(baseB + (size_t)s * DD + c4);
                    hv = actv4(bf4_to_f4(g), sc4, sh4);
                }
                const float* ep = eSr + f * DD + c4;
                acc[i].x += hv.x + ep[0]; acc[i].y += hv.y + ep[1];
                acc[i].z += hv.z + ep[2]; acc[i].w += hv.w + ep[3];
            }
        }
    }

    // ---- rdeg + bf16 hi/lo split -> LDS (write at original row index) ----
    #pragma unroll
    for (int i = 0; i < 4; i++) {
        int r = rows[i];
        float rd = rdeg[n0 + r];
        float ax = acc[i].x * rd, ay = acc[i].y * rd, az = acc[i].z * rd, aw = acc[i].w * rd;
        unsigned short h0 = f2bf(ax), h1 = f2bf(ay), h2 = f2bf(az), h3 = f2bf(aw);
        unsigned short l0 = f2bf(ax - bf2f(h0));
        unsigned short l1 = f2bf(ay - bf2f(h1));
        unsigned short l2 = f2bf(az - bf2f(h2));
        unsigned short l3 = f2bf(aw - bf2f(h3));
        uint2 hv2, lv2;
        hv2.x = (unsigned)h0 | ((unsigned)h1 << 16);
        hv2.y = (unsigned)h2 | ((unsigned)h3 << 16);
        lv2.x = (unsigned)l0 | ((unsigned)l1 << 16);
        lv2.y = (unsigned)l2 | ((unsigned)l3 << 16);
        *(uint2*)(Xh + r * XS + c4) = hv2;
        *(uint2*)(Xl + r * XS + c4) = lv2;
    }
    __syncthreads();

    // ---- MFMA: 4 waves; wave w -> row-tile (w&1), col-tiles (w>>1)*4..+3 ----
    int lane = tid & 63, w = tid >> 6;
    int m16 = lane & 15, quad = lane >> 4;
    int rowTile = w & 1;
    int colBase = (w >> 1) << 6;
    int rowA = rowTile * 16 + m16;

    floatx4 acc4[4];
    #pragma unroll
    for (int t = 0; t < 4; t++) acc4[t] = (floatx4){0.f, 0.f, 0.f, 0.f};

    #pragma unroll
    for (int kp = 0; kp < 4; kp++) {
        bf16x8 ah = *(const bf16x8*)(Xh + rowA * XS + kp * 32 + quad * 8);
        bf16x8 al = *(const bf16x8*)(Xl + rowA * XS + kp * 32 + quad * 8);
        #pragma unroll
        for (int t = 0; t < 4; t++) {
            int ncol = colBase + t * 16 + m16;
            bf16x8 bh = *(const bf16x8*)(Wht + (size_t)ncol * DD + kp * 32 + quad * 8);
            bf16x8 bl = *(const bf16x8*)(Wlt + (size_t)ncol * DD + kp * 32 + quad * 8);
            acc4[t] = __builtin_amdgcn_mfma_f32_16x16x32_bf16(ah, bh, acc4[t], 0, 0, 0);
            acc4[t] = __builtin_amdgcn_mfma_f32_16x16x32_bf16(ah, bl, acc4[t], 0, 0, 0);
            acc4[t] = __builtin_amdgcn_mfma_f32_16x16x32_bf16(al, bh, acc4[t], 0, 0, 0);
        }
    }
    __syncthreads();   // MFMA reads done -> Xh reusable as C buffer, eSr as red

    // ---- epilogue: bias, BN partials (fp32), pack bf16 C into LDS ----
    float* redS = eSr;
    float* redQ = eSr + 2 * DD;
    unsigned short* Cs = Xh;
    #pragma unroll
    for (int t = 0; t < 4; t++) {
        int col = colBase + t * 16 + m16;
        float bv = bias[col];
        float s = 0.f, q = 0.f;
        #pragma unroll
        for (int rr = 0; rr < 4; rr++) {
            float vv = acc4[t][rr] + bv;
            s += vv; q += vv * vv;
            Cs[(rowTile * 16 + quad * 4 + rr) * XS + col] = f2bf(vv);
        }
        s += __shfl_xor(s, 16); q += __shfl_xor(q, 16);
        s += __shfl_xor(s, 32); q += __shfl_xor(q, 32);
        if (lane < 16) { redS[rowTile * DD + col] = s; redQ[rowTile * DD + col] = q; }
    }
    __syncthreads();

    // ---- coalesced bf16 C store ----
    #pragma unroll
    for (int it = 0; it < 2; it++) {
        int idx = it * 256 + tid;          // 0..511
        int row = idx >> 4, q16 = idx & 15;
        uint4 v = *(const uint4*)(Cs + row * XS + q16 * 8);
        *(uint4*)(C + (size_t)(n0 + row) * DD + q16 * 8) = v;
    }

    // ---- sharded BN-stat atomics (musum layout: [256 rows][NSH]) ----
    int shard = blockIdx.x & (NSH - 1);
    if (tid < DD) {
        float ss = redS[tid] + redS[DD + tid];
        float qq = redQ[tid] + redQ[DD + tid];
        atomicAdd(&musum[(size_t)tid * NSH + shard], ss);
        atomicAdd(&musum[(size_t)(DD + tid) * NSH + shard], qq);
    }
    __threadfence();
    __syncthreads();
    if (tid == 0) lastF = (atomicAdd(cntL, 1) == NBLK - 1);
    __syncthreads();
    if (lastF) {
        // each thread reduces its row t over NSH shards (atomic reads -> L2-fresh)
        float s = 0.f;
        #pragma unroll
        for (int i = 0; i < NSH; i++)
            s += atomicAdd(&musum[(size_t)tid * NSH + i], 0.0f);
        eSr[tid] = s;
        __syncthreads();
        if (tid < DD) {
            float Sv = eSr[tid], Qv = eSr[DD + tid];
            float m = Sv / (float)NN;
            float v = Qv / (float)NN - m * m;
            float rs = rsqrtf(v + EPS);
            float sc = rs * gamC[tid];
            scO[tid] = sc;
            shO[tid] = betC[tid] - m * sc;
        }
    }
}

// ---------------- last layer: act fused with graph-sum pooling (bf16 h) ----------------
__global__ void k_bnpool(const unsigned short* __restrict__ A, const int* __restrict__ n2g,
                         const float* __restrict__ scale, const float* __restrict__ shift,
                         float* __restrict__ gsum) {
    int j = threadIdx.x;
    int n0 = blockIdx.x * CHUNK;
    float sc = scale[j], sh = shift[j];
    int cur = n2g[n0];
    float acc = 0.f;
    for (int i = 0; i < CHUNK; i++) {
        int n = n0 + i;
        int gg = n2g[n];
        if (gg != cur) {
            atomicAdd(&gsum[(size_t)cur * DD + j], acc);
            acc = 0.f;
            cur = gg;
        }
        float x = bf2f(A[(size_t)n * DD + j]);
        acc += fmaxf(0.f, x * sc + sh);
    }
    atomicAdd(&gsum[(size_t)cur * DD + j], acc);
}

// ---------------- final MLP ----------------
__global__ void k_mlp(const float* __restrict__ gsum, const float* __restrict__ gcnt,
                      const float* __restrict__ W1, const float* __restrict__ b1,
                      const float* __restrict__ W2, const float* __restrict__ b2,
                      float* __restrict__ out) {
    __shared__ float gs[DD], hs[DD];
    int gid = blockIdx.x, j = threadIdx.x;
    float inv = 1.0f / fmaxf(gcnt[gid], 1.0f);
    gs[j] = gsum[(size_t)gid * DD + j] * inv;
    __syncthreads();
    float a = b1[j];
    for (int k = 0; k < DD; k++) a += gs[k] * W1[k * DD + j];
    hs[j] = fmaxf(a, 0.f);
    __syncthreads();
    float o = b2[j];
    for (int k = 0; k < DD; k++) o += hs[k] * W2[k * DD + j];
    out[(size_t)gid * DD + j] = o;
}

extern "C" void kernel_launch(void* const* d_in, const int* in_sizes, int n_in,
                              void* d_out, int out_size, void* d_ws, size_t ws_size,
                              hipStream_t stream) {
    const int*   nfeat = (const int*)d_in[0];
    const int*   efeat = (const int*)d_in[1];
    const int*   src   = (const int*)d_in[2];
    const int*   dst   = (const int*)d_in[3];
    const int*   n2g   = (const int*)d_in[4];
    const float* aemb  = (const float*)d_in[5];
    const float* eemb  = (const float*)d_in[6];   // [L][5][128]
    const float* Wl    = (const float*)d_in[7];   // [L][128][128]
    const float* bl    = (const float*)d_in[8];   // [L][128]
    const float* gam   = (const float*)d_in[9];
    const float* bet   = (const float*)d_in[10];
    const float* W1    = (const float*)d_in[11];
    const float* b1    = (const float*)d_in[12];
    const float* W2    = (const float*)d_in[13];
    const float* b2    = (const float*)d_in[14];
    float* out = (float*)d_out;

    unsigned short* H0 = (unsigned short*)d_ws;          // NN*DD bf16
    unsigned short* H1 = H0 + (size_t)NN * DD;           // NN*DD bf16
    float* rdeg   = (float*)(H1 + (size_t)NN * DD);      // NN
    float* gsum   = rdeg + NN;                           // NG*DD
    float* gcnt   = gsum + (size_t)NG * DD;              // NG
    float* scaleA = gcnt + NG;                           // NL*DD
    float* shiftA = scaleA + NL * DD;                    // NL*DD
    float* accS   = shiftA + NL * DD;                    // NL*256*NSH
    int*   scnt   = (int*)(accS + (size_t)NL * 256 * NSH);  // 16
    unsigned short* Wht = (unsigned short*)(scnt + 16);  // NL*DD*DD
    unsigned short* Wlt = Wht + (size_t)NL * DD * DD;
    int* off   = (int*)(Wlt + (size_t)NL * DD * DD);     // NN+1
    int* cur   = off + NN + 1;                           // NN
    int* esrc  = cur + NN;                               // NE
    int* eft   = esrc + NE;                              // NE
    int* cnt   = eft + NE;                               // NN
    int* bsum  = cnt + NN;                               // NB_SCAN
    int* bpre  = bsum + NB_SCAN;                         // NB_SCAN
    int* bperm = bpre + NB_SCAN;                         // NBLK*32
    int* gmax  = bperm + (size_t)NBLK * BM;              // NBLK*8
    int* pent  = gmax + (size_t)NBLK * 8;                // NBLK*MAXD*BM (12.8 MB)
    int* pent0 = pent + (size_t)NBLK * MAXD * BM;        // NBLK*MAXD*BM (12.8 MB)

    hipMemsetAsync(gsum, 0, (size_t)(NG * DD + NG) * sizeof(float), stream);
    hipMemsetAsync(accS, 0, (size_t)(NL * 256 * NSH) * sizeof(float) + 16 * sizeof(int), stream);
    hipMemsetAsync(cnt, 0, (size_t)NN * sizeof(int), stream);

    k_setup1<<<(NE + 255) / 256, 256, 0, stream>>>(dst, cnt, n2g, gcnt, Wl, Wht, Wlt);
    k_scan1<<<NB_SCAN, 256, 0, stream>>>(cnt, bsum);
    k_scan2<<<1, 64, 0, stream>>>(bsum, bpre, off);
    k_scan3<<<NB_SCAN, 256, 0, stream>>>(cnt, bpre, off, cur, rdeg);
    k_bucket<<<(NE + 255) / 256, 256, 0, stream>>>(src, dst, efeat, cur, esrc, eft);
    k_pad<<<NBLK, 256, 0, stream>>>(off, esrc, eft, nfeat, pent, pent0, bperm, gmax);

    unsigned short* hcur = H0;
    for (int l = 0; l < NL; l++) {
        const void* base = (l == 0) ? (const void*)aemb : (const void*)hcur;
        unsigned short* hnext = (l == 0) ? H0 : ((hcur == H0) ? H1 : H0);
        const int* psel = (l == 0) ? pent0 : pent;
        const float* scP = scaleA + (size_t)((l == 0) ? 0 : (l - 1)) * DD;
        const float* shP = shiftA + (size_t)((l == 0) ? 0 : (l - 1)) * DD;
        k_fused<<<NBLK, 256, 0, stream>>>(base, nfeat, (l == 0) ? 1 : 0,
                                          off, esrc, eft, psel, bperm, gmax,
                                          eemb + (size_t)l * BOND_V * DD, rdeg,
                                          scP, shP,
                                          Wht + (size_t)l * DD * DD,
                                          Wlt + (size_t)l * DD * DD,
                                          bl + (size_t)l * DD, hnext,
                                          accS + (size_t)l * 256 * NSH, scnt + l,
                                          gam + (size_t)l * DD, bet + (size_t)l * DD,
                                          scaleA + (size_t)l * DD, shiftA + (size_t)l * DD);
        hcur = hnext;
    }
    k_bnpool<<<NN / CHUNK, DD, 0, stream>>>(hcur, n2g,
                                            scaleA + (size_t)(NL - 1) * DD,
                                            shiftA + (size_t)(NL - 1) * DD, gsum);
    k_mlp<<<NG, DD, 0, stream>>>(gsum, gcnt, W1, b1, W2, b2, out);
}

// Round 13
// 1039.468 us; speedup vs baseline: 3.7756x; 3.7756x over previous
//
#include <hip/hip_runtime.h>
#include <hip/hip_bf16.h>
#include <cstddef>

#define NN 200000   // nodes
#define NE 400000   // edges
#define DD 128      // embed dim
#define NL 5        // layers
#define NG 1000     // graphs
#define BOND_V 5
#define BM 32             // rows per fused block
#define NBLK (NN / BM)    // 6250
#define MAXD 16           // padded edge slots per row (deg>16 -> serial fallback)
#define CHUNK 100         // pool chunk (2000 blocks)
#define NB_SCAN 200
#define CH 1000
#define SB 125            // k_stats blocks (NBLK/SB = 50 rows each)
#define EPS 1e-5f
#define XS 136            // Xh/Xl row stride (shorts), 272B = 17*16 -> b128-aligned

typedef __bf16 bf16x8 __attribute__((ext_vector_type(8)));
typedef float floatx4 __attribute__((ext_vector_type(4)));

__device__ __forceinline__ unsigned short f2bf(float f) {
    unsigned int u = __float_as_uint(f);
    u = (u + 0x7fffu + ((u >> 16) & 1u)) >> 16;
    return (unsigned short)u;
}
__device__ __forceinline__ float bf2f(unsigned short s) {
    return __uint_as_float(((unsigned int)s) << 16);
}
__device__ __forceinline__ float4 bf4_to_f4(uint2 v) {
    float4 o;
    o.x = __uint_as_float(v.x << 16);
    o.y = __uint_as_float(v.x & 0xffff0000u);
    o.z = __uint_as_float(v.y << 16);
    o.w = __uint_as_float(v.y & 0xffff0000u);
    return o;
}
__device__ __forceinline__ float4 actv4(float4 h, float4 sc, float4 sh) {
    float4 o;
    o.x = fmaxf(0.f, h.x * sc.x + sh.x);
    o.y = fmaxf(0.f, h.y * sc.y + sh.y);
    o.z = fmaxf(0.f, h.z * sc.z + sh.z);
    o.w = fmaxf(0.f, h.w * sc.w + sh.w);
    return o;
}

// ---------------- merged setup: degree cnt, graph cnt, W split ----------------
__global__ void k_setup1(const int* __restrict__ dst, int* __restrict__ cnt,
                         const int* __restrict__ n2g, float* __restrict__ gcnt,
                         const float* __restrict__ W, unsigned short* __restrict__ Wht,
                         unsigned short* __restrict__ Wlt) {
    int e = blockIdx.x * blockDim.x + threadIdx.x;
    if (e < NE) atomicAdd(&cnt[dst[e]], 1);
    if (e < NN) atomicAdd(&gcnt[n2g[e]], 1.0f);
    if (e < NL * DD * DD) {
        int l = e / (DD * DD), rem = e % (DD * DD);
        int k = rem / DD, n = rem % DD;
        float v = W[e];
        unsigned short hb = f2bf(v);
        unsigned short lb = f2bf(v - bf2f(hb));
        size_t o = (size_t)l * DD * DD + (size_t)n * DD + k;
        Wht[o] = hb; Wlt[o] = lb;
    }
}

// ---------------- CSR build ----------------
__global__ void k_scan1(const int* __restrict__ cnt, int* __restrict__ bsum) {
    __shared__ int sh[256];
    int b = blockIdx.x, t = threadIdx.x;
    int s = 0;
    if (t < CH / 4) {
        int base = b * CH + t * 4;
        s = cnt[base] + cnt[base + 1] + cnt[base + 2] + cnt[base + 3];
    }
    sh[t] = s;
    __syncthreads();
    if (t == 0) {
        int tot = 0;
        for (int i = 0; i < CH / 4; i++) tot += sh[i];
        bsum[b] = tot;
    }
}

__global__ void k_scan2(const int* __restrict__ bsum, int* __restrict__ bpre,
                        int* __restrict__ off) {
    if (threadIdx.x == 0) {
        int run = 0;
        for (int i = 0; i < NB_SCAN; i++) { bpre[i] = run; run += bsum[i]; }
        off[NN] = NE;
    }
}

__global__ void k_scan3(const int* __restrict__ cnt, const int* __restrict__ bpre,
                        int* __restrict__ off, int* __restrict__ cur,
                        float* __restrict__ rdeg) {
    __shared__ int sh[256];
    int b = blockIdx.x, t = threadIdx.x;
    int base = b * CH + t * 4;
    int c0 = 0, c1 = 0, c2 = 0, c3 = 0, s = 0;
    if (t < CH / 4) {
        c0 = cnt[base]; c1 = cnt[base + 1]; c2 = cnt[base + 2]; c3 = cnt[base + 3];
        s = c0 + c1 + c2 + c3;
    }
    sh[t] = s;
    __syncthreads();
    if (t == 0) {
        int run = bpre[b];
        for (int i = 0; i < CH / 4; i++) { int v = sh[i]; sh[i] = run; run += v; }
    }
    __syncthreads();
    if (t < CH / 4) {
        int run = sh[t];
        off[base] = run; cur[base] = run; run += c0;
        off[base + 1] = run; cur[base + 1] = run; run += c1;
        off[base + 2] = run; cur[base + 2] = run; run += c2;
        off[base + 3] = run; cur[base + 3] = run;
        rdeg[base]     = 1.0f / (float)(c0 + 1);
        rdeg[base + 1] = 1.0f / (float)(c1 + 1);
        rdeg[base + 2] = 1.0f / (float)(c2 + 1);
        rdeg[base + 3] = 1.0f / (float)(c3 + 1);
    }
}

__global__ void k_bucket(const int* __restrict__ src, const int* __restrict__ dst,
                         const int* __restrict__ efeat, int* __restrict__ cur,
                         int* __restrict__ esrc, int* __restrict__ eft) {
    int e = blockIdx.x * blockDim.x + threadIdx.x;
    if (e < NE) {
        int p = atomicAdd(&cur[dst[e]], 1);
        esrc[p] = src[e];
        eft[p] = efeat[e];
    }
}

// ---------------- degree-sorted padded edge lists ----------------
// pent[b][j][32] = src | feat<<18 (layers 1+); pent0 = nfeat[src] | feat<<18 (layer 0)
// sentinel feat=5 (zero edge row, weight 0).
__global__ void k_pad(const int* __restrict__ off, const int* __restrict__ esrc,
                      const int* __restrict__ eft, const int* __restrict__ nfeat,
                      int* __restrict__ pent, int* __restrict__ pent0,
                      int* __restrict__ bperm, int* __restrict__ gmax) {
    __shared__ int offL[BM + 1];
    __shared__ int degS[BM];
    __shared__ int sortIdx[BM];
    __shared__ int gmaxS[8];
    int b = blockIdx.x, tid = threadIdx.x;
    if (tid <= BM) offL[tid] = off[b * BM + tid];
    __syncthreads();
    if (tid < BM) degS[tid] = offL[tid + 1] - offL[tid];
    __syncthreads();
    if (tid < BM) {
        int d = degS[tid], rank = 0;
        #pragma unroll
        for (int j = 0; j < BM; j++)
            rank += (degS[j] > d) || (degS[j] == d && j < tid);
        sortIdx[rank] = tid;
    }
    __syncthreads();
    if (tid < 8) {
        int g = degS[sortIdx[tid * 4]];   // sorted desc -> first in group is max
        gmaxS[tid] = g;
        gmax[b * 8 + tid] = g;
    }
    if (tid < BM) bperm[b * BM + tid] = sortIdx[tid];
    __syncthreads();
    for (int idx = tid; idx < BM * MAXD; idx += 256) {
        int p = idx & 31, j = idx >> 5, g = p >> 2;
        int gm = gmaxS[g]; if (gm > MAXD) gm = MAXD;
        if (j < gm) {
            int row = sortIdx[p];
            int d = degS[row];
            int v, v0;
            if (j < d) {
                int e = offL[row] + j;
                int s = esrc[e], f = eft[e];
                v = s | (f << 18);
                v0 = nfeat[s] | (f << 18);
            } else { v = (5 << 18); v0 = (5 << 18); }
            pent[(size_t)b * MAXD * BM + j * BM + p] = v;
            pent0[(size_t)b * MAXD * BM + j * BM + p] = v0;
        }
    }
}

// ---------------- fused layer (r9 structure: two-plane Xh/Xl, part[] epilogue) ----------------
__global__ __launch_bounds__(256, 4)
void k_fused(const void* __restrict__ basep, const int* __restrict__ nfeat, int first,
             const int* __restrict__ off, const int* __restrict__ esrc,
             const int* __restrict__ eft, const int* __restrict__ pentsel,
             const int* __restrict__ bperm, const int* __restrict__ gmax,
             const float* __restrict__ eemb, const float* __restrict__ rdeg,
             const float* __restrict__ scP, const float* __restrict__ shP,
             const unsigned short* __restrict__ Wht, const unsigned short* __restrict__ Wlt,
             const float* __restrict__ bias,
             unsigned short* __restrict__ C, float* __restrict__ part) {
    __shared__ unsigned short Xh[BM * XS];   // 8704 B (reused as C repack buffer)
    __shared__ unsigned short Xl[BM * XS];   // 8704 B
    __shared__ float eSr[6 * DD];            // 3072 B: eS in gather, red in epilogue
    __shared__ int pentL[BM * MAXD];         // 2048 B
    __shared__ int offL[BM + 1];
    __shared__ int permL[BM];
    __shared__ int gmL[8];

    const float* baseF = (const float*)basep;                   // first: atom_emb fp32
    const unsigned short* baseB = (const unsigned short*)basep; // else: h bf16

    int tid = threadIdx.x;
    int n0 = blockIdx.x * BM;
    if (tid < 160) *(float4*)(eSr + tid * 4) = *(const float4*)(eemb + tid * 4);
    else if (tid < 192) *(float4*)(eSr + tid * 4) = (float4){0.f, 0.f, 0.f, 0.f};
    if (tid <= BM) offL[tid] = off[n0 + tid];
    if (tid < BM) permL[tid] = bperm[blockIdx.x * BM + tid];
    if (tid < 8) gmL[tid] = gmax[blockIdx.x * 8 + tid];
    {
        const int2* pg = (const int2*)(pentsel + (size_t)blockIdx.x * MAXD * BM);
        *(int2*)(pentL + tid * 2) = pg[tid];
    }

    int lane32 = tid & 31, grp = tid >> 5;
    int c4 = lane32 << 2;
    float4 sc4, sh4;
    if (!first) {
        sc4 = *(const float4*)(scP + c4);
        sh4 = *(const float4*)(shP + c4);
    }
    __syncthreads();

    int rows[4];
    #pragma unroll
    for (int i = 0; i < 4; i++) rows[i] = permL[grp * 4 + i];

    // ---- self-init ----
    float4 acc[4];
    #pragma unroll
    for (int i = 0; i < 4; i++) {
        int n = n0 + rows[i];
        if (first) {
            acc[i] = *(const float4*)(baseF + (size_t)nfeat[n] * DD + c4);
        } else {
            uint2 g = *(const uint2*)(baseB + (size_t)n * DD + c4);
            acc[i] = actv4(bf4_to_f4(g), sc4, sh4);
        }
    }

    // ---- lockstep padded edge loop, unrolled x2, pent from LDS ----
    int gmx = gmL[grp];
    int jmax = gmx < MAXD ? gmx : MAXD;
    const int* pL = pentL + grp * 4;
    int j = 0;
    if (first) {
        for (; j + 2 <= jmax; j += 2) {
            int a0 = pL[j*32+0], a1 = pL[j*32+1], a2 = pL[j*32+2], a3 = pL[j*32+3];
            int b0 = pL[j*32+32], b1 = pL[j*32+33], b2 = pL[j*32+34], b3 = pL[j*32+35];
            float4 ha0 = *(const float4*)(baseF + (size_t)(a0 & 0x3FFFF) * DD + c4);
            float4 ha1 = *(const float4*)(baseF + (size_t)(a1 & 0x3FFFF) * DD + c4);
            float4 ha2 = *(const float4*)(baseF + (size_t)(a2 & 0x3FFFF) * DD + c4);
            float4 ha3 = *(const float4*)(baseF + (size_t)(a3 & 0x3FFFF) * DD + c4);
            float4 hb0 = *(const float4*)(baseF + (size_t)(b0 & 0x3FFFF) * DD + c4);
            float4 hb1 = *(const float4*)(baseF + (size_t)(b1 & 0x3FFFF) * DD + c4);
            float4 hb2 = *(const float4*)(baseF + (size_t)(b2 & 0x3FFFF) * DD + c4);
            float4 hb3 = *(const float4*)(baseF + (size_t)(b3 & 0x3FFFF) * DD + c4);
            int fa0 = a0 >> 18, fa1 = a1 >> 18, fa2 = a2 >> 18, fa3 = a3 >> 18;
            int fb0 = b0 >> 18, fb1 = b1 >> 18, fb2 = b2 >> 18, fb3 = b3 >> 18;
            float wa0 = (fa0 == 5) ? 0.f : 1.f, wa1 = (fa1 == 5) ? 0.f : 1.f;
            float wa2 = (fa2 == 5) ? 0.f : 1.f, wa3 = (fa3 == 5) ? 0.f : 1.f;
            float wb0 = (fb0 == 5) ? 0.f : 1.f, wb1 = (fb1 == 5) ? 0.f : 1.f;
            float wb2 = (fb2 == 5) ? 0.f : 1.f, wb3 = (fb3 == 5) ? 0.f : 1.f;
            float4 ea0 = *(const float4*)(eSr + fa0 * DD + c4);
            float4 ea1 = *(const float4*)(eSr + fa1 * DD + c4);
            float4 ea2 = *(const float4*)(eSr + fa2 * DD + c4);
            float4 ea3 = *(const float4*)(eSr + fa3 * DD + c4);
            float4 eb0 = *(const float4*)(eSr + fb0 * DD + c4);
            float4 eb1 = *(const float4*)(eSr + fb1 * DD + c4);
            float4 eb2 = *(const float4*)(eSr + fb2 * DD + c4);
            float4 eb3 = *(const float4*)(eSr + fb3 * DD + c4);
            acc[0].x += (ha0.x + ea0.x) * wa0 + (hb0.x + eb0.x) * wb0;
            acc[0].y += (ha0.y + ea0.y) * wa0 + (hb0.y + eb0.y) * wb0;
            acc[0].z += (ha0.z + ea0.z) * wa0 + (hb0.z + eb0.z) * wb0;
            acc[0].w += (ha0.w + ea0.w) * wa0 + (hb0.w + eb0.w) * wb0;
            acc[1].x += (ha1.x + ea1.x) * wa1 + (hb1.x + eb1.x) * wb1;
            acc[1].y += (ha1.y + ea1.y) * wa1 + (hb1.y + eb1.y) * wb1;
            acc[1].z += (ha1.z + ea1.z) * wa1 + (hb1.z + eb1.z) * wb1;
            acc[1].w += (ha1.w + ea1.w) * wa1 + (hb1.w + eb1.w) * wb1;
            acc[2].x += (ha2.x + ea2.x) * wa2 + (hb2.x + eb2.x) * wb2;
            acc[2].y += (ha2.y + ea2.y) * wa2 + (hb2.y + eb2.y) * wb2;
            acc[2].z += (ha2.z + ea2.z) * wa2 + (hb2.z + eb2.z) * wb2;
            acc[2].w += (ha2.w + ea2.w) * wa2 + (hb2.w + eb2.w) * wb2;
            acc[3].x += (ha3.x + ea3.x) * wa3 + (hb3.x + eb3.x) * wb3;
            acc[3].y += (ha3.y + ea3.y) * wa3 + (hb3.y + eb3.y) * wb3;
            acc[3].z += (ha3.z + ea3.z) * wa3 + (hb3.z + eb3.z) * wb3;
            acc[3].w += (ha3.w + ea3.w) * wa3 + (hb3.w + eb3.w) * wb3;
        }
        for (; j < jmax; j++) {
            int a0 = pL[j*32+0], a1 = pL[j*32+1], a2 = pL[j*32+2], a3 = pL[j*32+3];
            float4 h0 = *(const float4*)(baseF + (size_t)(a0 & 0x3FFFF) * DD + c4);
            float4 h1 = *(const float4*)(baseF + (size_t)(a1 & 0x3FFFF) * DD + c4);
            float4 h2 = *(const float4*)(baseF + (size_t)(a2 & 0x3FFFF) * DD + c4);
            float4 h3 = *(const float4*)(baseF + (size_t)(a3 & 0x3FFFF) * DD + c4);
            int f0 = a0 >> 18, f1 = a1 >> 18, f2 = a2 >> 18, f3 = a3 >> 18;
            float w0 = (f0 == 5) ? 0.f : 1.f, w1 = (f1 == 5) ? 0.f : 1.f;
            float w2 = (f2 == 5) ? 0.f : 1.f, w3 = (f3 == 5) ? 0.f : 1.f;
            float4 e0 = *(const float4*)(eSr + f0 * DD + c4);
            float4 e1 = *(const float4*)(eSr + f1 * DD + c4);
            float4 e2 = *(const float4*)(eSr + f2 * DD + c4);
            float4 e3 = *(const float4*)(eSr + f3 * DD + c4);
            acc[0].x += (h0.x + e0.x) * w0; acc[0].y += (h0.y + e0.y) * w0;
            acc[0].z += (h0.z + e0.z) * w0; acc[0].w += (h0.w + e0.w) * w0;
            acc[1].x += (h1.x + e1.x) * w1; acc[1].y += (h1.y + e1.y) * w1;
            acc[1].z += (h1.z + e1.z) * w1; acc[1].w += (h1.w + e1.w) * w1;
            acc[2].x += (h2.x + e2.x) * w2; acc[2].y += (h2.y + e2.y) * w2;
            acc[2].z += (h2.z + e2.z) * w2; acc[2].w += (h2.w + e2.w) * w2;
            acc[3].x += (h3.x + e3.x) * w3; acc[3].y += (h3.y + e3.y) * w3;
            acc[3].z += (h3.z + e3.z) * w3; acc[3].w += (h3.w + e3.w) * w3;
        }
    } else {
        for (; j + 2 <= jmax; j += 2) {
            int a0 = pL[j*32+0], a1 = pL[j*32+1], a2 = pL[j*32+2], a3 = pL[j*32+3];
            int b0 = pL[j*32+32], b1 = pL[j*32+33], b2 = pL[j*32+34], b3 = pL[j*32+35];
            uint2 ga0 = *(const uint2*)(baseB + (size_t)(a0 & 0x3FFFF) * DD + c4);
            uint2 ga1 = *(const uint2*)(baseB + (size_t)(a1 & 0x3FFFF) * DD + c4);
            uint2 ga2 = *(const uint2*)(baseB + (size_t)(a2 & 0x3FFFF) * DD + c4);
            uint2 ga3 = *(const uint2*)(baseB + (size_t)(a3 & 0x3FFFF) * DD + c4);
            uint2 gb0 = *(const uint2*)(baseB + (size_t)(b0 & 0x3FFFF) * DD + c4);
            uint2 gb1 = *(const uint2*)(baseB + (size_t)(b1 & 0x3FFFF) * DD + c4);
            uint2 gb2 = *(const uint2*)(baseB + (size_t)(b2 & 0x3FFFF) * DD + c4);
            uint2 gb3 = *(const uint2*)(baseB + (size_t)(b3 & 0x3FFFF) * DD + c4);
            float4 ha0 = actv4(bf4_to_f4(ga0), sc4, sh4);
            float4 ha1 = actv4(bf4_to_f4(ga1), sc4, sh4);
            float4 ha2 = actv4(bf4_to_f4(ga2), sc4, sh4);
            float4 ha3 = actv4(bf4_to_f4(ga3), sc4, sh4);
            float4 hb0 = actv4(bf4_to_f4(gb0), sc4, sh4);
            float4 hb1 = actv4(bf4_to_f4(gb1), sc4, sh4);
            float4 hb2 = actv4(bf4_to_f4(gb2), sc4, sh4);
            float4 hb3 = actv4(bf4_to_f4(gb3), sc4, sh4);
            int fa0 = a0 >> 18, fa1 = a1 >> 18, fa2 = a2 >> 18, fa3 = a3 >> 18;
            int fb0 = b0 >> 18, fb1 = b1 >> 18, fb2 = b2 >> 18, fb3 = b3 >> 18;
            float wa0 = (fa0 == 5) ? 0.f : 1.f, wa1 = (fa1 == 5) ? 0.f : 1.f;
            float wa2 = (fa2 == 5) ? 0.f : 1.f, wa3 = (fa3 == 5) ? 0.f : 1.f;
            float wb0 = (fb0 == 5) ? 0.f : 1.f, wb1 = (fb1 == 5) ? 0.f : 1.f;
            float wb2 = (fb2 == 5) ? 0.f : 1.f, wb3 = (fb3 == 5) ? 0.f : 1.f;
            float4 ea0 = *(const float4*)(eSr + fa0 * DD + c4);
            float4 ea1 = *(const float4*)(eSr + fa1 * DD + c4);
            float4 ea2 = *(const float4*)(eSr + fa2 * DD + c4);
            float4 ea3 = *(const float4*)(eSr + fa3 * DD + c4);
            float4 eb0 = *(const float4*)(eSr + fb0 * DD + c4);
            float4 eb1 = *(const float4*)(eSr + fb1 * DD + c4);
            float4 eb2 = *(const float4*)(eSr + fb2 * DD + c4);
            float4 eb3 = *(const float4*)(eSr + fb3 * DD + c4);
            acc[0].x += (ha0.x + ea0.x) * wa0 + (hb0.x + eb0.x) * wb0;
            acc[0].y += (ha0.y + ea0.y) * wa0 + (hb0.y + eb0.y) * wb0;
            acc[0].z += (ha0.z + ea0.z) * wa0 + (hb0.z + eb0.z) * wb0;
            acc[0].w += (ha0.w + ea0.w) * wa0 + (hb0.w + eb0.w) * wb0;
            acc[1].x += (ha1.x + ea1.x) * wa1 + (hb1.x + eb1.x) * wb1;
            acc[1].y += (ha1.y + ea1.y) * wa1 + (hb1.y + eb1.y) * wb1;
            acc[1].z += (ha1.z + ea1.z) * wa1 + (hb1.z + eb1.z) * wb1;
            acc[1].w += (ha1.w + ea1.w) * wa1 + (hb1.w + eb1.w) * wb1;
            acc[2].x += (ha2.x + ea2.x) * wa2 + (hb2.x + eb2.x) * wb2;
            acc[2].y += (ha2.y + ea2.y) * wa2 + (hb2.y + eb2.y) * wb2;
            acc[2].z += (ha2.z + ea2.z) * wa2 + (hb2.z + eb2.z) * wb2;
            acc[2].w += (ha2.w + ea2.w) * wa2 + (hb2.w + eb2.w) * wb2;
            acc[3].x += (ha3.x + ea3.x) * wa3 + (hb3.x + eb3.x) * wb3;
            acc[3].y += (ha3.y + ea3.y) * wa3 + (hb3.y + eb3.y) * wb3;
            acc[3].z += (ha3.z + ea3.z) * wa3 + (hb3.z + eb3.z) * wb3;
            acc[3].w += (ha3.w + ea3.w) * wa3 + (hb3.w + eb3.w) * wb3;
        }
        for (; j < jmax; j++) {
            int a0 = pL[j*32+0], a1 = pL[j*32+1], a2 = pL[j*32+2], a3 = pL[j*32+3];
            uint2 g0 = *(const uint2*)(baseB + (size_t)(a0 & 0x3FFFF) * DD + c4);
            uint2 g1 = *(const uint2*)(baseB + (size_t)(a1 & 0x3FFFF) * DD + c4);
            uint2 g2 = *(const uint2*)(baseB + (size_t)(a2 & 0x3FFFF) * DD + c4);
            uint2 g3 = *(const uint2*)(baseB + (size_t)(a3 & 0x3FFFF) * DD + c4);
            float4 h0 = actv4(bf4_to_f4(g0), sc4, sh4);
            float4 h1 = actv4(bf4_to_f4(g1), sc4, sh4);
            float4 h2 = actv4(bf4_to_f4(g2), sc4, sh4);
            float4 h3 = actv4(bf4_to_f4(g3), sc4, sh4);
            int f0 = a0 >> 18, f1 = a1 >> 18, f2 = a2 >> 18, f3 = a3 >> 18;
            float w0 = (f0 == 5) ? 0.f : 1.f, w1 = (f1 == 5) ? 0.f : 1.f;
            float w2 = (f2 == 5) ? 0.f : 1.f, w3 = (f3 == 5) ? 0.f : 1.f;
            float4 e0 = *(const float4*)(eSr + f0 * DD + c4);
            float4 e1 = *(const float4*)(eSr + f1 * DD + c4);
            float4 e2 = *(const float4*)(eSr + f2 * DD + c4);
            float4 e3 = *(const float4*)(eSr + f3 * DD + c4);
            acc[0].x += (h0.x + e0.x) * w0; acc[0].y += (h0.y + e0.y) * w0;
            acc[0].z += (h0.z + e0.z) * w0; acc[0].w += (h0.w + e0.w) * w0;
            acc[1].x += (h1.x + e1.x) * w1; acc[1].y += (h1.y + e1.y) * w1;
            acc[1].z += (h1.z + e1.z) * w1; acc[1].w += (h1.w + e1.w) * w1;
            acc[2].x += (h2.x + e2.x) * w2; acc[2].y += (h2.y + e2.y) * w2;
            acc[2].z += (h2.z + e2.z) * w2; acc[2].w += (h2.w + e2.w) * w2;
            acc[3].x += (h3.x + e3.x) * w3; acc[3].y += (h3.y + e3.y) * w3;
            acc[3].z += (h3.z + e3.z) * w3; acc[3].w += (h3.w + e3.w) * w3;
        }
    }

    // ---- rare fallback: rows with deg > MAXD ----
    if (gmx > MAXD) {
        #pragma unroll
        for (int i = 0; i < 4; i++) {
            int row = rows[i];
            for (int e = offL[row] + MAXD; e < offL[row + 1]; e++) {
                int s = esrc[e], f = eft[e];
                float4 hv;
                if (first) {
                    hv = *(const float4*)(baseF + (size_t)nfeat[s] * DD + c4);
                } else {
                    uint2 g = *(const uint2*)(baseB + (size_t)s * DD + c4);
                    hv = actv4(bf4_to_f4(g), sc4, sh4);
                }
                const float* ep = eSr + f * DD + c4;
                acc[i].x += hv.x + ep[0]; acc[i].y += hv.y + ep[1];
                acc[i].z += hv.z + ep[2]; acc[i].w += hv.w + ep[3];
            }
        }
    }

    // ---- rdeg + bf16 hi/lo split -> LDS (write at original row index) ----
    #pragma unroll
    for (int i = 0; i < 4; i++) {
        int r = rows[i];
        float rd = rdeg[n0 + r];
        float ax = acc[i].x * rd, ay = acc[i].y * rd, az = acc[i].z * rd, aw = acc[i].w * rd;
        unsigned short h0 = f2bf(ax), h1 = f2bf(ay), h2 = f2bf(az), h3 = f2bf(aw);
        unsigned short l0 = f2bf(ax - bf2f(h0));
        unsigned short l1 = f2bf(ay - bf2f(h1));
        unsigned short l2 = f2bf(az - bf2f(h2));
        unsigned short l3 = f2bf(aw - bf2f(h3));
        uint2 hv2, lv2;
        hv2.x = (unsigned)h0 | ((unsigned)h1 << 16);
        hv2.y = (unsigned)h2 | ((unsigned)h3 << 16);
        lv2.x = (unsigned)l0 | ((unsigned)l1 << 16);
        lv2.y = (unsigned)l2 | ((unsigned)l3 << 16);
        *(uint2*)(Xh + r * XS + c4) = hv2;
        *(uint2*)(Xl + r * XS + c4) = lv2;
    }
    __syncthreads();

    // ---- MFMA: 4 waves; wave w -> row-tile (w&1), col-tiles (w>>1)*4..+3 ----
    int lane = tid & 63, w = tid >> 6;
    int m16 = lane & 15, quad = lane >> 4;
    int rowTile = w & 1;
    int colBase = (w >> 1) << 6;
    int rowA = rowTile * 16 + m16;

    floatx4 acc4[4];
    #pragma unroll
    for (int t = 0; t < 4; t++) acc4[t] = (floatx4){0.f, 0.f, 0.f, 0.f};

    #pragma unroll
    for (int kp = 0; kp < 4; kp++) {
        bf16x8 ah = *(const bf16x8*)(Xh + rowA * XS + kp * 32 + quad * 8);
        bf16x8 al = *(const bf16x8*)(Xl + rowA * XS + kp * 32 + quad * 8);
        #pragma unroll
        for (int t = 0; t < 4; t++) {
            int ncol = colBase + t * 16 + m16;
            bf16x8 bh = *(const bf16x8*)(Wht + (size_t)ncol * DD + kp * 32 + quad * 8);
            bf16x8 bl = *(const bf16x8*)(Wlt + (size_t)ncol * DD + kp * 32 + quad * 8);
            acc4[t] = __builtin_amdgcn_mfma_f32_16x16x32_bf16(ah, bh, acc4[t], 0, 0, 0);
            acc4[t] = __builtin_amdgcn_mfma_f32_16x16x32_bf16(ah, bl, acc4[t], 0, 0, 0);
            acc4[t] = __builtin_amdgcn_mfma_f32_16x16x32_bf16(al, bh, acc4[t], 0, 0, 0);
        }
    }
    __syncthreads();   // MFMA reads done -> Xh reusable as C buffer, eSr as red

    // ---- epilogue: bias, BN partials (fp32), pack bf16 C into LDS ----
    float* redS = eSr;
    float* redQ = eSr + 2 * DD;
    unsigned short* Cs = Xh;
    #pragma unroll
    for (int t = 0; t < 4; t++) {
        int col = colBase + t * 16 + m16;
        float bv = bias[col];
        float s = 0.f, q = 0.f;
        #pragma unroll
        for (int rr = 0; rr < 4; rr++) {
            float vv = acc4[t][rr] + bv;
            s += vv; q += vv * vv;
            Cs[(rowTile * 16 + quad * 4 + rr) * XS + col] = f2bf(vv);
        }
        s += __shfl_xor(s, 16); q += __shfl_xor(q, 16);
        s += __shfl_xor(s, 32); q += __shfl_xor(q, 32);
        if (lane < 16) { redS[rowTile * DD + col] = s; redQ[rowTile * DD + col] = q; }
    }
    __syncthreads();

    // ---- coalesced bf16 C store ----
    #pragma unroll
    for (int it = 0; it < 2; it++) {
        int idx = it * 256 + tid;          // 0..511
        int row = idx >> 4, q16 = idx & 15;
        uint4 v = *(const uint4*)(Cs + row * XS + q16 * 8);
        *(uint4*)(C + (size_t)(n0 + row) * DD + q16 * 8) = v;
    }
    if (tid < DD) {
        float ss = redS[tid] + redS[DD + tid];
        float qq = redQ[tid] + redQ[DD + tid];
        part[(size_t)blockIdx.x * 256 + tid] = ss;
        part[(size_t)blockIdx.x * 256 + DD + tid] = qq;
    }
}

// ---------------- BN stat reduce + last-block finalize -> scale/shift ----------------
__global__ void k_stats(const float* __restrict__ part, float* __restrict__ acc,
                        int* __restrict__ cnt,
                        const float* __restrict__ gamma, const float* __restrict__ beta,
                        float* __restrict__ scale, float* __restrict__ shift) {
    int t = threadIdx.x;
    float s = 0.f;
    int base = blockIdx.x * (NBLK / SB);
    for (int i = 0; i < NBLK / SB; i++)
        s += part[(size_t)(base + i) * 256 + t];
    atomicAdd(&acc[t], s);
    __threadfence();
    __shared__ int lastS;
    __syncthreads();
    if (t == 0) lastS = (atomicAdd(cnt, 1) == SB - 1);
    __syncthreads();
    if (lastS && t < DD) {
        float Sv = atomicAdd(&acc[t], 0.0f);
        float Qv = atomicAdd(&acc[DD + t], 0.0f);
        float m = Sv / (float)NN;
        float v = Qv / (float)NN - m * m;
        float rs = rsqrtf(v + EPS);
        float sc = rs * gamma[t];
        scale[t] = sc;
        shift[t] = beta[t] - m * sc;
    }
}

// ---------------- last layer: act fused with graph-sum pooling (bf16 h) ----------------
__global__ void k_bnpool(const unsigned short* __restrict__ A, const int* __restrict__ n2g,
                         const float* __restrict__ scale, const float* __restrict__ shift,
                         float* __restrict__ gsum) {
    int j = threadIdx.x;
    int n0 = blockIdx.x * CHUNK;
    float sc = scale[j], sh = shift[j];
    int cur = n2g[n0];
    float acc = 0.f;
    for (int i = 0; i < CHUNK; i++) {
        int n = n0 + i;
        int gg = n2g[n];
        if (gg != cur) {
            atomicAdd(&gsum[(size_t)cur * DD + j], acc);
            acc = 0.f;
            cur = gg;
        }
        float x = bf2f(A[(size_t)n * DD + j]);
        acc += fmaxf(0.f, x * sc + sh);
    }
    atomicAdd(&gsum[(size_t)cur * DD + j], acc);
}

// ---------------- final MLP ----------------
__global__ void k_mlp(const float* __restrict__ gsum, const float* __restrict__ gcnt,
                      const float* __restrict__ W1, const float* __restrict__ b1,
                      const float* __restrict__ W2, const float* __restrict__ b2,
                      float* __restrict__ out) {
    __shared__ float gs[DD], hs[DD];
    int gid = blockIdx.x, j = threadIdx.x;
    float inv = 1.0f / fmaxf(gcnt[gid], 1.0f);
    gs[j] = gsum[(size_t)gid * DD + j] * inv;
    __syncthreads();
    float a = b1[j];
    for (int k = 0; k < DD; k++) a += gs[k] * W1[k * DD + j];
    hs[j] = fmaxf(a, 0.f);
    __syncthreads();
    float o = b2[j];
    for (int k = 0; k < DD; k++) o += hs[k] * W2[k * DD + j];
    out[(size_t)gid * DD + j] = o;
}

extern "C" void kernel_launch(void* const* d_in, const int* in_sizes, int n_in,
                              void* d_out, int out_size, void* d_ws, size_t ws_size,
                              hipStream_t stream) {
    const int*   nfeat = (const int*)d_in[0];
    const int*   efeat = (const int*)d_in[1];
    const int*   src   = (const int*)d_in[2];
    const int*   dst   = (const int*)d_in[3];
    const int*   n2g   = (const int*)d_in[4];
    const float* aemb  = (const float*)d_in[5];
    const float* eemb  = (const float*)d_in[6];   // [L][5][128]
    const float* Wl    = (const float*)d_in[7];   // [L][128][128]
    const float* bl    = (const float*)d_in[8];   // [L][128]
    const float* gam   = (const float*)d_in[9];
    const float* bet   = (const float*)d_in[10];
    const float* W1    = (const float*)d_in[11];
    const float* b1    = (const float*)d_in[12];
    const float* W2    = (const float*)d_in[13];
    const float* b2    = (const float*)d_in[14];
    float* out = (float*)d_out;

    unsigned short* H0 = (unsigned short*)d_ws;          // NN*DD bf16
    unsigned short* H1 = H0 + (size_t)NN * DD;           // NN*DD bf16
    float* rdeg   = (float*)(H1 + (size_t)NN * DD);      // NN
    float* gsum   = rdeg + NN;                           // NG*DD
    float* gcnt   = gsum + (size_t)NG * DD;              // NG
    float* scaleA = gcnt + NG;                           // NL*DD
    float* shiftA = scaleA + NL * DD;                    // NL*DD
    float* accS   = shiftA + NL * DD;                    // NL*256
    int*   scnt   = (int*)(accS + NL * 256);             // 16
    float* part   = (float*)(scnt + 16);                 // NBLK*256 floats (6.4 MB)
    unsigned short* Wht = (unsigned short*)(part + (size_t)NBLK * 256);  // NL*DD*DD
    unsigned short* Wlt = Wht + (size_t)NL * DD * DD;
    int* off   = (int*)(Wlt + (size_t)NL * DD * DD);     // NN+1
    int* cur   = off + NN + 1;                           // NN
    int* esrc  = cur + NN;                               // NE
    int* eft   = esrc + NE;                              // NE
    int* cnt   = eft + NE;                               // NN
    int* bsum  = cnt + NN;                               // NB_SCAN
    int* bpre  = bsum + NB_SCAN;                         // NB_SCAN
    int* bperm = bpre + NB_SCAN;                         // NBLK*32
    int* gmax  = bperm + (size_t)NBLK * BM;              // NBLK*8
    int* pent  = gmax + (size_t)NBLK * 8;                // NBLK*MAXD*BM (12.8 MB)
    int* pent0 = pent + (size_t)NBLK * MAXD * BM;        // NBLK*MAXD*BM (12.8 MB)

    hipMemsetAsync(gsum, 0, (size_t)(NG * DD + NG) * sizeof(float), stream);
    hipMemsetAsync(accS, 0, (size_t)(NL * 256) * sizeof(float) + 16 * sizeof(int), stream);
    hipMemsetAsync(cnt, 0, (size_t)NN * sizeof(int), stream);

    k_setup1<<<(NE + 255) / 256, 256, 0, stream>>>(dst, cnt, n2g, gcnt, Wl, Wht, Wlt);
    k_scan1<<<NB_SCAN, 256, 0, stream>>>(cnt, bsum);
    k_scan2<<<1, 64, 0, stream>>>(bsum, bpre, off);
    k_scan3<<<NB_SCAN, 256, 0, stream>>>(cnt, bpre, off, cur, rdeg);
    k_bucket<<<(NE + 255) / 256, 256, 0, stream>>>(src, dst, efeat, cur, esrc, eft);
    k_pad<<<NBLK, 256, 0, stream>>>(off, esrc, eft, nfeat, pent, pent0, bperm, gmax);

    unsigned short* hcur = H0;
    for (int l = 0; l < NL; l++) {
        const void* base = (l == 0) ? (const void*)aemb : (const void*)hcur;
        unsigned short* hnext = (l == 0) ? H0 : ((hcur == H0) ? H1 : H0);
        const int* psel = (l == 0) ? pent0 : pent;
        const float* scP = scaleA + (size_t)((l == 0) ? 0 : (l - 1)) * DD;
        const float* shP = shiftA + (size_t)((l == 0) ? 0 : (l - 1)) * DD;
        k_fused<<<NBLK, 256, 0, stream>>>(base, nfeat, (l == 0) ? 1 : 0,
                                          off, esrc, eft, psel, bperm, gmax,
                                          eemb + (size_t)l * BOND_V * DD, rdeg,
                                          scP, shP,
                                          Wht + (size_t)l * DD * DD,
                                          Wlt + (size_t)l * DD * DD,
                                          bl + (size_t)l * DD, hnext, part);
        k_stats<<<SB, 256, 0, stream>>>(part, accS + l * 256, scnt + l,
                                        gam + (size_t)l * DD, bet + (size_t)l * DD,
                                        scaleA + (size_t)l * DD, shiftA + (size_t)l * DD);
        hcur = hnext;
    }
    k_bnpool<<<NN / CHUNK, DD, 0, stream>>>(hcur, n2g,
                                            scaleA + (size_t)(NL - 1) * DD,
                                            shiftA + (size_t)(NL - 1) * DD, gsum);
    k_mlp<<<NG, DD, 0, stream>>>(gsum, gcnt, W1, b1, W2, b2, out);
}